// Round 10
// baseline (5304.625 us; speedup 1.0000x reference)
//
#include <hip/hip_runtime.h>

// SPDReLU via matrix-sign:  relu_spd(P) = (P + P*sign(P))/2.
// R10: belt-and-braces. Evidence across R1-R9: every straight-line MFMA
// construct worked (R8 diagnostics, R9 gate); every branched/unrolled MFMA
// production region silently became C-passthrough (out=0.5P, absmax
// 4.804688 bit-identical in R6/R7/R9) despite fences. So: (1) the MFMA
// sign-loop is straight-line and ROLLED (#pragma unroll 1 -> one
// gate-shaped body executed 9x); (2) the epilogue is proven VALU mm16
// (no MFMA consumer); (3) a functional S^2~I check on the REAL data
// gates per-wave fallback to the proven full-VALU path. Every mechanical
// failure mode funnels into the fallback => PASS guaranteed; duration
// encodes which path ran (~0.8ms fast vs ~4.5ms fallback).

typedef float f32x4 __attribute__((ext_vector_type(4)));
typedef __bf16 bf16x8 __attribute__((ext_vector_type(8)));
typedef unsigned short us4v __attribute__((ext_vector_type(4)));
typedef unsigned short us8v __attribute__((ext_vector_type(8)));

union FragU { unsigned short u[8]; us8v v; bf16x8 f; };

#define LDS_FENCE()                                        \
  do {                                                     \
    asm volatile("s_waitcnt lgkmcnt(0)" ::: "memory");     \
    __builtin_amdgcn_sched_barrier(0);                     \
  } while (0)

__device__ __forceinline__ unsigned short f2b(float x) {
  return __builtin_bit_cast(unsigned short, (__bf16)x);
}

// LDS column stride (u16): 24 -> 48 B; keeps 16B alignment for b128 reads,
// 2-way bank aliasing only (free per m136).
#define LDSS 24

// wide-margin sign schedule: 6x g5PE, g6PE, g7, g8(NS5)
__device__ const float g_Ak[9] = {2.300652019954817f, 2.300652019954817f,
                                  2.300652019954817f, 2.300652019954817f,
                                  2.300652019954817f, 2.300652019954817f,
                                  1.891301407787398f, 1.8750014808534479f,
                                  1.875f};
__device__ const float g_Bk[9] = {-1.6689039845747493f, -1.6689039845747493f,
                                  -1.6689039845747493f, -1.6689039845747493f,
                                  -1.6689039845747493f, -1.6689039845747493f,
                                  -1.2679958271945868f, -1.2500016453999487f,
                                  -1.25f};
__device__ const float g_Ck[9] = {0.4188073119525673f, 0.4188073119525673f,
                                  0.4188073119525673f, 0.4188073119525673f,
                                  0.4188073119525673f, 0.4188073119525673f,
                                  0.37680408948524835f, 0.3750001645474248f,
                                  0.375f};

__device__ __forceinline__ void store_cd(unsigned short* buf, f32x4 cd,
                                         float scale, int c, int g) {
  us4v t;
#pragma unroll
  for (int r = 0; r < 4; ++r) t[r] = f2b(cd[r] * scale);
  *reinterpret_cast<us4v*>(&buf[LDSS * c + 4 * g]) = t;
}

// B natural: slot (h=g,e) holds M[8*(g&1)+e][c]  (one ds_read_b128).
__device__ __forceinline__ bf16x8 readB(const unsigned short* buf, int c, int g) {
  FragU fu;
  fu.v = *reinterpret_cast<const us8v*>(&buf[LDSS * c + 8 * (g & 1)]);
  return fu.f;
}

// A calibrated: slot e holds M[j[e]][c]  (8x ds_read_u16).
__device__ __forceinline__ bf16x8 readA(const unsigned short* buf, int c,
                                        const int* j) {
  FragU fu;
#pragma unroll
  for (int e = 0; e < 8; ++e) fu.u[e] = buf[LDSS * c + j[e]];
  return fu.f;
}

// One quintic step x -> a*x + b*x^3 + c*x^5 (3 MFMAs), fenced.
__device__ __forceinline__ f32x4 body(f32x4 x, float a, float b, float cc,
                                      unsigned short* buf0,
                                      unsigned short* buf1, const int* j,
                                      int c, int g) {
  const f32x4 zero = {0.f, 0.f, 0.f, 0.f};
  store_cd(buf0, x, 1.0f, c, g);
  LDS_FENCE();
  bf16x8 fax = readA(buf0, c, j);
  bf16x8 fbx = readB(buf0, c, g);
  f32x4 y = __builtin_amdgcn_mfma_f32_16x16x32_bf16(fax, fbx, zero, 0, 0, 0);

  store_cd(buf1, y, 1.0f, c, g);
  LDS_FENCE();
  const float beta = 4.0f * b / cc;
  f32x4 acc0 = {beta * y[0], beta * y[1], beta * y[2], beta * y[3]};
  bf16x8 fay = readA(buf1, c, j);
  bf16x8 fby = readB(buf1, c, g);
  f32x4 w = __builtin_amdgcn_mfma_f32_16x16x32_bf16(fay, fby, acc0, 0, 0, 0);

  store_cd(buf1, w, cc * 0.0625f, c, g);
  LDS_FENCE();
  f32x4 acc1 = {a * x[0], a * x[1], a * x[2], a * x[3]};
  bf16x8 fbw = readB(buf1, c, g);
  return __builtin_amdgcn_mfma_f32_16x16x32_bf16(fax, fbw, acc1, 0, 0, 0);
}

// -------- proven VALU 16x16 matmul (R5): d[r] = (A*B)[4g+r][c] --------
__device__ __forceinline__ void mm16(const float a[4], const float b[4],
                                     float d[4], int c, int g) {
  d[0] = 0.f; d[1] = 0.f; d[2] = 0.f; d[3] = 0.f;
#pragma unroll
  for (int k = 0; k < 16; ++k) {
    float bk = __shfl(b[k & 3], c + ((k >> 2) << 4), 64);
#pragma unroll
    for (int r = 0; r < 4; ++r) {
      float ak = __shfl(a[r], (g << 4) + k, 64);
      d[r] = fmaf(ak, bk, d[r]);
    }
  }
}

__global__ __launch_bounds__(256) void spdrelu_r10(
    const float* __restrict__ P, float* __restrict__ OUT, int nmat) {
  __shared__ __align__(16) unsigned short lds[4][2][16 * LDSS];
  const int lane = threadIdx.x & 63;
  const int wid  = threadIdx.x >> 6;
  const int mat  = blockIdx.x * 4 + wid;
  if (mat >= nmat) return;

  const int c = lane & 15;
  const int g = lane >> 4;
  unsigned short* buf0 = lds[wid][0];
  unsigned short* buf1 = lds[wid][1];
  const f32x4 zero = {0.f, 0.f, 0.f, 0.f};

  // ---------- calibration (straight-line, C=zero: R8-proven) ----------
  FragU a1, a2, tg;
#pragma unroll
  for (int e = 0; e < 8; ++e) {
    a1.u[e] = ((g < 2) && (c == 8 * (g & 1) + e)) ? f2b(1.0f) : (unsigned short)0;
    a2.u[e] = ((g >= 2) && (c == 8 * (g & 1) + e)) ? f2b(1.0f) : (unsigned short)0;
    tg.u[e] = f2b((float)(8 * g + e));
  }
  f32x4 d1 = __builtin_amdgcn_mfma_f32_16x16x32_bf16(a1.f, tg.f, zero, 0, 0, 0);
  f32x4 d2 = __builtin_amdgcn_mfma_f32_16x16x32_bf16(a2.f, tg.f, zero, 0, 0, 0);
  int j[8];
#pragma unroll
  for (int e = 0; e < 8; ++e) {
    int src = 32 * (g & 1) + 16 * (e >> 2);
    float t1 = __shfl(d1[e & 3], src, 64);
    float t2 = __shfl(d2[e & 3], src, 64);
    float ts = fminf(fmaxf((g < 2) ? t1 : t2, 0.f), 31.f);
    j[e] = ((int)ts) & 15;
  }

  // ---------- load & normalize ----------
  const float* Pm = P + (size_t)mat * 256;
  f32x4 p, x;
#pragma unroll
  for (int r = 0; r < 4; ++r) p[r] = Pm[(4 * g + r) * 16 + c];
  float nrm = p[0] * p[0] + p[1] * p[1] + p[2] * p[2] + p[3] * p[3];
#pragma unroll
  for (int off = 32; off; off >>= 1) nrm += __shfl_xor(nrm, off, 64);
  const float inv = 0.97f * rsqrtf(fmaxf(nrm, 1e-30f));
#pragma unroll
  for (int r = 0; r < 4; ++r) x[r] = p[r] * inv;

  // ---------- MFMA sign loop: straight-line, ROLLED ----------
#pragma unroll 1
  for (int it = 0; it < 9; ++it)
    x = body(x, g_Ak[it], g_Bk[it], g_Ck[it], buf0, buf1, j, c, g);

  // ---------- functional check on real data: S^2 ~ I (proven VALU) ----------
  float xa[4] = {x[0], x[1], x[2], x[3]};
  float pa[4] = {p[0], p[1], p[2], p[3]};
  float ss[4];
  mm16(xa, xa, ss, c, g);
  int okS = 1;
#pragma unroll
  for (int r = 0; r < 4; ++r) {
    float idv = (4 * g + r == c) ? 1.0f : 0.0f;
    float dd = fabsf(ss[r] - idv);
    okS &= (dd <= 0.25f) ? 1 : 0;  // NaN -> false -> 0
  }
#pragma unroll
  for (int off = 32; off; off >>= 1) {
    int o = __shfl_xor(okS, off, 64);
    okS = okS < o ? okS : o;
  }

  // ---------- epilogue: out = (P + P*S)/2 via proven VALU mm16 ----------
  float outv[4];
  {
    float ps[4];
    mm16(pa, xa, ps, c, g);
#pragma unroll
    for (int r = 0; r < 4; ++r) outv[r] = 0.5f * (pa[r] + ps[r]);
  }

  if (!okS) {
    // ---------- fallback: full proven VALU path from scratch ----------
    float xv[4];
#pragma unroll
    for (int r = 0; r < 4; ++r) xv[r] = pa[r] * inv;
#pragma unroll 1
    for (int it = 0; it < 9; ++it) {
      float y[4], y2[4], w[4], xw[4];
      mm16(xv, xv, y, c, g);
      mm16(y, y, y2, c, g);
#pragma unroll
      for (int r = 0; r < 4; ++r) w[r] = g_Bk[it] * y[r] + g_Ck[it] * y2[r];
      mm16(xv, w, xw, c, g);
#pragma unroll
      for (int r = 0; r < 4; ++r) xv[r] = g_Ak[it] * xv[r] + xw[r];
    }
    float ps[4];
    mm16(pa, xv, ps, c, g);
#pragma unroll
    for (int r = 0; r < 4; ++r) outv[r] = 0.5f * (pa[r] + ps[r]);
  }

  float* Om = OUT + (size_t)mat * 256;
#pragma unroll
  for (int r = 0; r < 4; ++r) Om[(4 * g + r) * 16 + c] = outv[r];
}

extern "C" void kernel_launch(void* const* d_in, const int* in_sizes, int n_in,
                              void* d_out, int out_size, void* d_ws,
                              size_t ws_size, hipStream_t stream) {
  (void)n_in; (void)out_size; (void)d_ws; (void)ws_size;
  const float* P = (const float*)d_in[0];
  float* OUT = (float*)d_out;
  const int nmat = in_sizes[0] / 256;
  const int blocks = (nmat + 3) / 4;  // 4 waves = 4 matrices per block
  spdrelu_r10<<<dim3(blocks), dim3(256), 0, stream>>>(P, OUT, nmat);
}

// Round 11
// 1847.406 us; speedup vs baseline: 2.8714x; 2.8714x over previous
//
#include <hip/hip_runtime.h>

// SPDReLU via matrix-sign (Polar Express 8-step), optimized pure-VALU.
//   relu_spd(P) = (P + P*sign(P))/2   (differs from eigh-clamp by <= 1e-4)
// R11: MFMA abandoned after 6 rounds of context-dependent silent corruption
// (single straight-line instances provably work; any loop/branch context
// yields C-passthrough garbage -- unobservable codegen issue). This kernel
// uses only hardware-proven primitives: ds_bpermute (__shfl) + fp32 fma.
// Restructured from R5 (1 matrix/wave, 80 shfl/mm) to 4 matrices/wave with
// 4x4 register tiles: outer-product mm = 128 shfl + 256 fma per wave-mm
// serving 4 matrices (2.5x fewer DS ops, 4x fewer waves).
//
// Layout: lane l: q=l>>4 (matrix in wave), t=l&15, a=t>>2, b=t&3.
// Lane owns tile M[4a+s][4b+u], s,u=0..3 (16 VGPRs per matrix-state).
// mm: C[4a+s][4b+u] = sum_k A[4a+s][k]*B[k][4b+u]; for k=4kb+kr:
//   A-val = x[s][kr] of lane 16q+4a+kb, B-val = x[kr][u] of lane 16q+4kb+b.

__device__ const float g_Ak[8] = {8.28721201814563f,  4.107059111542203f,
                                  3.9486908534822946f, 3.3184196573706015f,
                                  2.300652019954817f,  1.891301407787398f,
                                  1.8750014808534479f, 1.875f};
__device__ const float g_Bk[8] = {-23.595886519098837f, -2.9478499167379106f,
                                  -2.908902115962949f,  -2.488488024314874f,
                                  -1.6689039845747493f, -1.2679958271945868f,
                                  -1.2500016453999487f, -1.25f};
__device__ const float g_Ck[8] = {17.300387312530933f, 0.5448431082926601f,
                                  0.5518191394370137f, 0.51004894012372f,
                                  0.4188073119525673f, 0.37680408948524835f,
                                  0.3750001645474248f, 0.375f};

// acc += A*B over the 16-wide K, 4 matrices per wave simultaneously.
__device__ __forceinline__ void mmw(const float a[4][4], const float b[4][4],
                                    float acc[4][4], int abase, int bbase) {
#pragma unroll
  for (int kb = 0; kb < 4; ++kb) {
    const int as = abase + kb;      // lane holding A[4a+s][4kb+kr]
    const int bs = bbase + 4 * kb;  // lane holding B[4kb+kr][4b+u]
#pragma unroll
    for (int kr = 0; kr < 4; ++kr) {
      float av[4], bv[4];
#pragma unroll
      for (int s = 0; s < 4; ++s) av[s] = __shfl(a[s][kr], as, 64);
#pragma unroll
      for (int u = 0; u < 4; ++u) bv[u] = __shfl(b[kr][u], bs, 64);
#pragma unroll
      for (int s = 0; s < 4; ++s)
#pragma unroll
        for (int u = 0; u < 4; ++u)
          acc[s][u] = fmaf(av[s], bv[u], acc[s][u]);
    }
  }
}

__global__ __launch_bounds__(256) void spdrelu_r11(
    const float* __restrict__ P, float* __restrict__ OUT, int nmat) {
  const int lane = threadIdx.x & 63;
  const int wid  = threadIdx.x >> 6;
  const int mat4 = (blockIdx.x * 4 + wid) * 4;  // first matrix of this wave
  if (mat4 >= nmat) return;                     // wave-uniform guard

  const int q = lane >> 4;
  const int t = lane & 15;
  const int a = t >> 2;
  const int b = t & 3;
  const int abase = 16 * q + 4 * a;  // + kb
  const int bbase = 16 * q + b;      // + 4*kb
  const int mat = mat4 + q;

  // ---- load 4x4 tile (float4 rows; 64 lanes cover 4 KB contiguously) ----
  const float* Pm = P + (size_t)mat * 256;
  float p[4][4];
#pragma unroll
  for (int s = 0; s < 4; ++s)
    *reinterpret_cast<float4*>(&p[s][0]) =
        *reinterpret_cast<const float4*>(&Pm[(4 * a + s) * 16 + 4 * b]);

  // ---- per-matrix Frobenius norm (16-lane group reduce) ----
  float nrm = 0.f;
#pragma unroll
  for (int s = 0; s < 4; ++s)
#pragma unroll
    for (int u = 0; u < 4; ++u) nrm = fmaf(p[s][u], p[s][u], nrm);
#pragma unroll
  for (int off = 1; off < 16; off <<= 1) nrm += __shfl_xor(nrm, off, 64);
  const float inv = 0.97f * rsqrtf(fmaxf(nrm, 1e-30f));

  float x[4][4];
#pragma unroll
  for (int s = 0; s < 4; ++s)
#pragma unroll
    for (int u = 0; u < 4; ++u) x[s][u] = p[s][u] * inv;

  // ---- Polar Express 8-step quintic: x <- a*x + b*x^3 + c*x^5 ----
#pragma unroll 1
  for (int it = 0; it < 8; ++it) {
    const float ak = g_Ak[it], bk = g_Bk[it], ck = g_Ck[it];
    const float boc = bk / ck;

    float y[4][4];
#pragma unroll
    for (int s = 0; s < 4; ++s)
#pragma unroll
      for (int u = 0; u < 4; ++u) y[s][u] = 0.f;
    mmw(x, x, y, abase, bbase);  // y = X^2

    float w[4][4];
#pragma unroll
    for (int s = 0; s < 4; ++s)
#pragma unroll
      for (int u = 0; u < 4; ++u) w[s][u] = boc * y[s][u];
    mmw(y, y, w, abase, bbase);  // w = (b/c)Y + Y^2
#pragma unroll
    for (int s = 0; s < 4; ++s)
#pragma unroll
      for (int u = 0; u < 4; ++u) w[s][u] *= ck;  // w = b*Y + c*Y^2

    float xn[4][4];
#pragma unroll
    for (int s = 0; s < 4; ++s)
#pragma unroll
      for (int u = 0; u < 4; ++u) xn[s][u] = ak * x[s][u];
    mmw(x, w, xn, abase, bbase);  // xn = a*X + X*(b*Y + c*Y^2)
#pragma unroll
    for (int s = 0; s < 4; ++s)
#pragma unroll
      for (int u = 0; u < 4; ++u) x[s][u] = xn[s][u];
  }

  // ---- out = 0.5*(P + P*S) ----
  float o[4][4];
#pragma unroll
  for (int s = 0; s < 4; ++s)
#pragma unroll
    for (int u = 0; u < 4; ++u) o[s][u] = p[s][u];
  mmw(p, x, o, abase, bbase);  // o = P + P*S

  float* Om = OUT + (size_t)mat * 256;
#pragma unroll
  for (int s = 0; s < 4; ++s) {
    float4 v;
    v.x = 0.5f * o[s][0];
    v.y = 0.5f * o[s][1];
    v.z = 0.5f * o[s][2];
    v.w = 0.5f * o[s][3];
    *reinterpret_cast<float4*>(&Om[(4 * a + s) * 16 + 4 * b]) = v;
  }
}

extern "C" void kernel_launch(void* const* d_in, const int* in_sizes, int n_in,
                              void* d_out, int out_size, void* d_ws,
                              size_t ws_size, hipStream_t stream) {
  (void)n_in; (void)out_size; (void)d_ws; (void)ws_size;
  const float* P = (const float*)d_in[0];
  float* OUT = (float*)d_out;
  const int nmat = in_sizes[0] / 256;
  const int blocks = (nmat + 15) / 16;  // 4 waves x 4 matrices per block
  spdrelu_r11<<<dim3(blocks), dim3(256), 0, stream>>>(P, OUT, nmat);
}

// Round 12
// 1149.884 us; speedup vs baseline: 4.6132x; 1.6066x over previous
//
#include <hip/hip_runtime.h>

// SPDReLU via matrix-sign (Polar Express 8-step), pure-VALU+DS pipe-split.
//   relu_spd(P) = (P + P*sign(P))/2
// R12: R11 was ds_bpermute-throughput-bound (3200 bperm/wave ~= 2ms, matches
// counters). Pipe-split mm: A-import via DPP quad_perm broadcast (VALU pipe,
// tile(a,kb) lives in the lane's own quad), B-import via ds_read_b128 from
// LDS (4 vals/op + free 4-way broadcast). Algebra reshaped so every mm's
// B-operand is X or Y only (T=X*Y, V=T*Y, X'=aX+bT+cV; polynomials in P
// commute) -> one LDS buffer/wave, 8 writes/iter. DPP (new primitive) gated
// by the proven-mmw S^2~I oracle with full R11 fallback: PASS guaranteed.

typedef float f4v __attribute__((ext_vector_type(4)));

__device__ const float g_Ak[8] = {8.28721201814563f,  4.107059111542203f,
                                  3.9486908534822946f, 3.3184196573706015f,
                                  2.300652019954817f,  1.891301407787398f,
                                  1.8750014808534479f, 1.875f};
__device__ const float g_Bk[8] = {-23.595886519098837f, -2.9478499167379106f,
                                  -2.908902115962949f,  -2.488488024314874f,
                                  -1.6689039845747493f, -1.2679958271945868f,
                                  -1.2500016453999487f, -1.25f};
__device__ const float g_Ck[8] = {17.300387312530933f, 0.5448431082926601f,
                                  0.5518191394370137f, 0.51004894012372f,
                                  0.4188073119525673f, 0.37680408948524835f,
                                  0.3750001645474248f, 0.375f};

#define LDS_FENCE()                                        \
  do {                                                     \
    asm volatile("s_waitcnt lgkmcnt(0)" ::: "memory");     \
    __builtin_amdgcn_sched_barrier(0);                     \
  } while (0)

// Broadcast from quad position kb (DPP quad_perm, VALU pipe).
__device__ __forceinline__ float dppbc(float v, int kb) {
  int iv = __builtin_bit_cast(int, v), r;
  switch (kb & 3) {
    case 0:  r = __builtin_amdgcn_update_dpp(0, iv, 0x00, 0xF, 0xF, true); break;
    case 1:  r = __builtin_amdgcn_update_dpp(0, iv, 0x55, 0xF, 0xF, true); break;
    case 2:  r = __builtin_amdgcn_update_dpp(0, iv, 0xAA, 0xF, 0xF, true); break;
    default: r = __builtin_amdgcn_update_dpp(0, iv, 0xFF, 0xF, 0xF, true); break;
  }
  return __builtin_bit_cast(float, r);
}

// LDS: 16 slabs/wave, slab id = q + 4*gridrow (gridrow = a on write, kb on
// read), slab stride 148 floats (592B: 16B-aligned, 4*148 mod 32 spreads
// banks), within slab: kr*36 + 4*chunk. Conflicts <= 3-way.
#define SLABS 148
#define WBUF  2368  // 16*148 floats per wave

__device__ __forceinline__ void storeT(float* buf, const float M[4][4], int q,
                                       int a, int b) {
  const int o = (q + 4 * a) * SLABS + 4 * b;
#pragma unroll
  for (int s = 0; s < 4; ++s)
    *reinterpret_cast<f4v*>(&buf[o + s * 36]) =
        *reinterpret_cast<const f4v*>(&M[s][0]);
}

// acc[s][u] += sum_k A[4a+s][k] * B[k][4b+u];  A from regs via DPP, B from LDS.
__device__ __forceinline__ void mmL(const float A[4][4], const float* buf,
                                    float acc[4][4], int q, int b) {
  const int base = q * SLABS + 4 * b;
#pragma unroll
  for (int kb = 0; kb < 4; ++kb) {
#pragma unroll
    for (int kr = 0; kr < 4; ++kr) {
      f4v bv = *reinterpret_cast<const f4v*>(
          &buf[base + kb * (4 * SLABS) + kr * 36]);
      float a0 = dppbc(A[0][kr], kb);
      float a1 = dppbc(A[1][kr], kb);
      float a2 = dppbc(A[2][kr], kb);
      float a3 = dppbc(A[3][kr], kb);
#pragma unroll
      for (int u = 0; u < 4; ++u) {
        acc[0][u] = fmaf(a0, bv[u], acc[0][u]);
        acc[1][u] = fmaf(a1, bv[u], acc[1][u]);
        acc[2][u] = fmaf(a2, bv[u], acc[2][u]);
        acc[3][u] = fmaf(a3, bv[u], acc[3][u]);
      }
    }
  }
}

// -------- proven R11 bpermute mm (oracle + fallback) --------
__device__ __forceinline__ void mmw(const float a[4][4], const float b[4][4],
                                    float acc[4][4], int abase, int bbase) {
#pragma unroll
  for (int kb = 0; kb < 4; ++kb) {
    const int as = abase + kb;
    const int bs = bbase + 4 * kb;
#pragma unroll
    for (int kr = 0; kr < 4; ++kr) {
      float av[4], bv[4];
#pragma unroll
      for (int s = 0; s < 4; ++s) av[s] = __shfl(a[s][kr], as, 64);
#pragma unroll
      for (int u = 0; u < 4; ++u) bv[u] = __shfl(b[kr][u], bs, 64);
#pragma unroll
      for (int s = 0; s < 4; ++s)
#pragma unroll
        for (int u = 0; u < 4; ++u)
          acc[s][u] = fmaf(av[s], bv[u], acc[s][u]);
    }
  }
}

__global__ __launch_bounds__(256) void spdrelu_r12(
    const float* __restrict__ P, float* __restrict__ OUT, int nmat) {
  __shared__ float lds[4][WBUF];
  const int lane = threadIdx.x & 63;
  const int wid  = threadIdx.x >> 6;
  const int mat4 = (blockIdx.x * 4 + wid) * 4;
  if (mat4 >= nmat) return;

  const int q = lane >> 4, t = lane & 15, a = t >> 2, b = t & 3;
  float* buf = lds[wid];
  const int mat  = mat4 + q;
  const int matc = mat < nmat ? mat : nmat - 1;

  // ---- load 4x4 tile ----
  const float* Pm = P + (size_t)matc * 256;
  float p[4][4];
#pragma unroll
  for (int s = 0; s < 4; ++s)
    *reinterpret_cast<f4v*>(&p[s][0]) =
        *reinterpret_cast<const f4v*>(&Pm[(4 * a + s) * 16 + 4 * b]);

  // ---- per-matrix Frobenius norm (16-lane reduce) ----
  float nrm = 0.f;
#pragma unroll
  for (int s = 0; s < 4; ++s)
#pragma unroll
    for (int u = 0; u < 4; ++u) nrm = fmaf(p[s][u], p[s][u], nrm);
#pragma unroll
  for (int off = 1; off < 16; off <<= 1) nrm += __shfl_xor(nrm, off, 64);
  const float inv = 0.97f * rsqrtf(fmaxf(nrm, 1e-30f));

  float x[4][4];
#pragma unroll
  for (int s = 0; s < 4; ++s)
#pragma unroll
    for (int u = 0; u < 4; ++u) x[s][u] = p[s][u] * inv;

  // ---- PE-8: X' = aX + bT + cV with T = X*Y, V = T*Y, Y = X^2 ----
#pragma unroll 1
  for (int it = 0; it < 8; ++it) {
    const float ak = g_Ak[it], bk = g_Bk[it], ck = g_Ck[it];

    storeT(buf, x, q, a, b);
    LDS_FENCE();
    float y[4][4] = {};
    mmL(x, buf, y, q, b);       // Y = X^2   (B = X in LDS)

    storeT(buf, y, q, a, b);    // overwrite with Y (y-stores depend on reads)
    LDS_FENCE();
    float tm[4][4] = {};
    mmL(x, buf, tm, q, b);      // T = X*Y = X^3
    float v[4][4] = {};
    mmL(tm, buf, v, q, b);      // V = T*Y = X^5

#pragma unroll
    for (int s = 0; s < 4; ++s)
#pragma unroll
      for (int u = 0; u < 4; ++u)
        x[s][u] = fmaf(ak, x[s][u], fmaf(bk, tm[s][u], ck * v[s][u]));
  }

  // ---- epilogue: o = P + P*S (B = S in LDS) ----
  storeT(buf, x, q, a, b);
  LDS_FENCE();
  float o[4][4];
#pragma unroll
  for (int s = 0; s < 4; ++s)
#pragma unroll
    for (int u = 0; u < 4; ++u) o[s][u] = p[s][u];
  mmL(p, buf, o, q, b);

  // ---- oracle: S^2 ~ I via PROVEN bpermute mm ----
  const int abase = 16 * q + 4 * a, bbase = 16 * q + b;
  float ss[4][4] = {};
  mmw(x, x, ss, abase, bbase);
  int okS = 1;
#pragma unroll
  for (int s = 0; s < 4; ++s)
#pragma unroll
    for (int u = 0; u < 4; ++u) {
      float idv = (4 * a + s == 4 * b + u) ? 1.0f : 0.0f;
      okS &= (fabsf(ss[s][u] - idv) <= 0.25f) ? 1 : 0;  // NaN -> 0
    }
#pragma unroll
  for (int off = 1; off < 16; off <<= 1) {
    int oo = __shfl_xor(okS, off, 64);
    okS = okS < oo ? okS : oo;
  }

  if (!okS) {
    // ---- fallback: full proven R11 path ----
    float xa[4][4];
#pragma unroll
    for (int s = 0; s < 4; ++s)
#pragma unroll
      for (int u = 0; u < 4; ++u) xa[s][u] = p[s][u] * inv;
#pragma unroll 1
    for (int it = 0; it < 8; ++it) {
      const float ak = g_Ak[it], bk = g_Bk[it], ck = g_Ck[it];
      float y[4][4] = {};
      mmw(xa, xa, y, abase, bbase);
      float w[4][4];
#pragma unroll
      for (int s = 0; s < 4; ++s)
#pragma unroll
        for (int u = 0; u < 4; ++u) w[s][u] = (bk / ck) * y[s][u];
      mmw(y, y, w, abase, bbase);
      float xn[4][4];
#pragma unroll
      for (int s = 0; s < 4; ++s)
#pragma unroll
        for (int u = 0; u < 4; ++u) xn[s][u] = ak * xa[s][u];
#pragma unroll
      for (int s = 0; s < 4; ++s)
#pragma unroll
        for (int u = 0; u < 4; ++u) w[s][u] *= ck;
      mmw(xa, w, xn, abase, bbase);
#pragma unroll
      for (int s = 0; s < 4; ++s)
#pragma unroll
        for (int u = 0; u < 4; ++u) xa[s][u] = xn[s][u];
    }
#pragma unroll
    for (int s = 0; s < 4; ++s)
#pragma unroll
      for (int u = 0; u < 4; ++u) o[s][u] = p[s][u];
    mmw(p, xa, o, abase, bbase);
  }

  if (mat < nmat) {
    float* Om = OUT + (size_t)mat * 256;
#pragma unroll
    for (int s = 0; s < 4; ++s) {
      f4v vv;
#pragma unroll
      for (int u = 0; u < 4; ++u) vv[u] = 0.5f * o[s][u];
      *reinterpret_cast<f4v*>(&Om[(4 * a + s) * 16 + 4 * b]) = vv;
    }
  }
}

extern "C" void kernel_launch(void* const* d_in, const int* in_sizes, int n_in,
                              void* d_out, int out_size, void* d_ws,
                              size_t ws_size, hipStream_t stream) {
  (void)n_in; (void)out_size; (void)d_ws; (void)ws_size;
  const float* P = (const float*)d_in[0];
  float* OUT = (float*)d_out;
  const int nmat = in_sizes[0] / 256;
  const int blocks = (nmat + 15) / 16;  // 4 waves x 4 matrices per block
  spdrelu_r12<<<dim3(blocks), dim3(256), 0, stream>>>(P, OUT, nmat);
}

// Round 13
// 717.818 us; speedup vs baseline: 7.3899x; 1.6019x over previous
//
#include <hip/hip_runtime.h>

// SPDReLU via matrix-sign (Polar Express, 6 steps + checked fallback).
//   relu_spd(P) = (P + P*sign(P))/2
// R13: from R12 (proven DPP-A + LDS-B mmL): (1) 6 iterations (traced: full
// convergence envelope within threshold; outliers caught by S^2-check ->
// 8-iter fp32 fallback); (2) refactored iter T=Y*X reuses B=X in LDS ->
// 2 stores+2 fences/iter; (3) oracle via mmL (16 reads) not 128 bpermutes;
// (4) slab stride 148->84 (same mod-32 banks, 0-conflict proven) -> 21.5KB
// LDS/block; VGPR down -> occupancy up. Check+fallback keeps PASS guaranteed.

typedef float f4v __attribute__((ext_vector_type(4)));

__device__ const float g_Ak[8] = {8.28721201814563f,  4.107059111542203f,
                                  3.9486908534822946f, 3.3184196573706015f,
                                  2.300652019954817f,  1.891301407787398f,
                                  1.8750014808534479f, 1.875f};
__device__ const float g_Bk[8] = {-23.595886519098837f, -2.9478499167379106f,
                                  -2.908902115962949f,  -2.488488024314874f,
                                  -1.6689039845747493f, -1.2679958271945868f,
                                  -1.2500016453999487f, -1.25f};
__device__ const float g_Ck[8] = {17.300387312530933f, 0.5448431082926601f,
                                  0.5518191394370137f, 0.51004894012372f,
                                  0.4188073119525673f, 0.37680408948524835f,
                                  0.3750001645474248f, 0.375f};

#define LDS_FENCE()                                        \
  do {                                                     \
    asm volatile("s_waitcnt lgkmcnt(0)" ::: "memory");     \
    __builtin_amdgcn_sched_barrier(0);                     \
  } while (0)

// Broadcast from quad position kb (DPP quad_perm, VALU pipe). Proven R12.
__device__ __forceinline__ float dppbc(float v, int kb) {
  int iv = __builtin_bit_cast(int, v), r;
  switch (kb & 3) {
    case 0:  r = __builtin_amdgcn_update_dpp(0, iv, 0x00, 0xF, 0xF, true); break;
    case 1:  r = __builtin_amdgcn_update_dpp(0, iv, 0x55, 0xF, 0xF, true); break;
    case 2:  r = __builtin_amdgcn_update_dpp(0, iv, 0xAA, 0xF, 0xF, true); break;
    default: r = __builtin_amdgcn_update_dpp(0, iv, 0xFF, 0xF, 0xF, true); break;
  }
  return __builtin_bit_cast(float, r);
}

// LDS: 16 slabs/wave (id = q + 4*gridrow), stride 84 floats (same mod-32
// bank residues as R12's proven 148), rows at kr*20 (16B aligned).
#define SLABS 84
#define WBUF  1344  // 16*84 floats per wave = 5376 B

__device__ __forceinline__ void storeT(float* buf, const float M[4][4], int q,
                                       int a, int b) {
  const int o = (q + 4 * a) * SLABS + 4 * b;
#pragma unroll
  for (int s = 0; s < 4; ++s)
    *reinterpret_cast<f4v*>(&buf[o + s * 20]) =
        *reinterpret_cast<const f4v*>(&M[s][0]);
}

// acc[s][u] += sum_k A[4a+s][k]*B[k][4b+u]; A regs via DPP, B from LDS.
__device__ __forceinline__ void mmL(const float A[4][4], const float* buf,
                                    float acc[4][4], int q, int b) {
  const int base = q * SLABS + 4 * b;
#pragma unroll
  for (int kb = 0; kb < 4; ++kb) {
#pragma unroll
    for (int kr = 0; kr < 4; ++kr) {
      f4v bv = *reinterpret_cast<const f4v*>(
          &buf[base + kb * (4 * SLABS) + kr * 20]);
      float a0 = dppbc(A[0][kr], kb);
      float a1 = dppbc(A[1][kr], kb);
      float a2 = dppbc(A[2][kr], kb);
      float a3 = dppbc(A[3][kr], kb);
#pragma unroll
      for (int u = 0; u < 4; ++u) {
        acc[0][u] = fmaf(a0, bv[u], acc[0][u]);
        acc[1][u] = fmaf(a1, bv[u], acc[1][u]);
        acc[2][u] = fmaf(a2, bv[u], acc[2][u]);
        acc[3][u] = fmaf(a3, bv[u], acc[3][u]);
      }
    }
  }
}

// -------- proven R11 bpermute mm (cold fallback only) --------
__device__ __forceinline__ void mmw(const float a[4][4], const float b[4][4],
                                    float acc[4][4], int abase, int bbase) {
#pragma unroll
  for (int kb = 0; kb < 4; ++kb) {
    const int as = abase + kb;
    const int bs = bbase + 4 * kb;
#pragma unroll
    for (int kr = 0; kr < 4; ++kr) {
      float av[4], bv[4];
#pragma unroll
      for (int s = 0; s < 4; ++s) av[s] = __shfl(a[s][kr], as, 64);
#pragma unroll
      for (int u = 0; u < 4; ++u) bv[u] = __shfl(b[kr][u], bs, 64);
#pragma unroll
      for (int s = 0; s < 4; ++s)
#pragma unroll
        for (int u = 0; u < 4; ++u)
          acc[s][u] = fmaf(av[s], bv[u], acc[s][u]);
    }
  }
}

__global__ __launch_bounds__(256) void spdrelu_r13(
    const float* __restrict__ P, float* __restrict__ OUT, int nmat) {
  __shared__ float lds[4][WBUF];
  const int lane = threadIdx.x & 63;
  const int wid  = threadIdx.x >> 6;
  const int mat4 = (blockIdx.x * 4 + wid) * 4;
  if (mat4 >= nmat) return;

  const int q = lane >> 4, t = lane & 15, a = t >> 2, b = t & 3;
  float* buf = lds[wid];
  const int mat  = mat4 + q;
  const int matc = mat < nmat ? mat : nmat - 1;

  // ---- load 4x4 tile ----
  const float* Pm = P + (size_t)matc * 256;
  float p[4][4];
#pragma unroll
  for (int s = 0; s < 4; ++s)
    *reinterpret_cast<f4v*>(&p[s][0]) =
        *reinterpret_cast<const f4v*>(&Pm[(4 * a + s) * 16 + 4 * b]);

  // ---- per-matrix Frobenius norm (16-lane reduce) ----
  float nrm = 0.f;
#pragma unroll
  for (int s = 0; s < 4; ++s)
#pragma unroll
    for (int u = 0; u < 4; ++u) nrm = fmaf(p[s][u], p[s][u], nrm);
#pragma unroll
  for (int off = 1; off < 16; off <<= 1) nrm += __shfl_xor(nrm, off, 64);
  const float inv = 0.97f * rsqrtf(fmaxf(nrm, 1e-30f));

  float x[4][4];
#pragma unroll
  for (int s = 0; s < 4; ++s)
#pragma unroll
    for (int u = 0; u < 4; ++u) x[s][u] = p[s][u] * inv;

  storeT(buf, x, q, a, b);
  LDS_FENCE();

  // ---- 6 steps: Y=X^2 (B=X); T=Y*X=X^3 (B=X); X' = aX + T*(bI+cY) ----
#pragma unroll 1
  for (int it = 0; it < 6; ++it) {
    const float ak = g_Ak[it], bk = g_Bk[it], ck = g_Ck[it];

    float y[4][4] = {};
    mmL(x, buf, y, q, b);        // Y = X^2
    float tm[4][4] = {};
    mmL(y, buf, tm, q, b);       // T = Y*X = X^3  (same B=X stream)

    float d[4][4];
#pragma unroll
    for (int s = 0; s < 4; ++s)
#pragma unroll
      for (int u = 0; u < 4; ++u) d[s][u] = ck * y[s][u];
    if (a == b) {
#pragma unroll
      for (int s = 0; s < 4; ++s) d[s][s] += bk;   // D = bI + cY
    }
    storeT(buf, d, q, a, b);
    LDS_FENCE();

    float xn[4][4];
#pragma unroll
    for (int s = 0; s < 4; ++s)
#pragma unroll
      for (int u = 0; u < 4; ++u) xn[s][u] = ak * x[s][u];
    mmL(tm, buf, xn, q, b);      // X' = aX + T*D = aX + bX^3 + cX^5
#pragma unroll
    for (int s = 0; s < 4; ++s)
#pragma unroll
      for (int u = 0; u < 4; ++u) x[s][u] = xn[s][u];

    storeT(buf, x, q, a, b);     // serves next iter / epilogue / check
    LDS_FENCE();
  }

  // ---- check: S^2 ~ I via mmL (B=S already in LDS) ----
  float ss[4][4] = {};
  mmL(x, buf, ss, q, b);
  int okS = 1;
#pragma unroll
  for (int s = 0; s < 4; ++s)
#pragma unroll
    for (int u = 0; u < 4; ++u) {
      float idv = (4 * a + s == 4 * b + u) ? 1.0f : 0.0f;
      okS &= (fabsf(ss[s][u] - idv) <= 0.25f) ? 1 : 0;  // NaN -> 0
    }
#pragma unroll
  for (int off = 1; off < 16; off <<= 1) {
    int oo = __shfl_xor(okS, off, 64);
    okS = okS < oo ? okS : oo;
  }

  // ---- epilogue: o = P + P*S (B=S in LDS) ----
  float o[4][4];
#pragma unroll
  for (int s = 0; s < 4; ++s)
#pragma unroll
    for (int u = 0; u < 4; ++u) o[s][u] = p[s][u];
  mmL(p, buf, o, q, b);

  if (!okS) {
    // ---- cold fallback: proven R11 bpermute path, full 8 iterations ----
    const int abase = 16 * q + 4 * a, bbase = 16 * q + b;
    float xa[4][4];
#pragma unroll
    for (int s = 0; s < 4; ++s)
#pragma unroll
      for (int u = 0; u < 4; ++u) xa[s][u] = p[s][u] * inv;
#pragma unroll 1
    for (int it = 0; it < 8; ++it) {
      const float ak = g_Ak[it], bk = g_Bk[it], ck = g_Ck[it];
      float y[4][4] = {};
      mmw(xa, xa, y, abase, bbase);
      float w[4][4];
#pragma unroll
      for (int s = 0; s < 4; ++s)
#pragma unroll
        for (int u = 0; u < 4; ++u) w[s][u] = (bk / ck) * y[s][u];
      mmw(y, y, w, abase, bbase);
      float xn[4][4];
#pragma unroll
      for (int s = 0; s < 4; ++s)
#pragma unroll
        for (int u = 0; u < 4; ++u) xn[s][u] = ak * xa[s][u];
#pragma unroll
      for (int s = 0; s < 4; ++s)
#pragma unroll
        for (int u = 0; u < 4; ++u) w[s][u] *= ck;
      mmw(xa, w, xn, abase, bbase);
#pragma unroll
      for (int s = 0; s < 4; ++s)
#pragma unroll
        for (int u = 0; u < 4; ++u) xa[s][u] = xn[s][u];
    }
#pragma unroll
    for (int s = 0; s < 4; ++s)
#pragma unroll
      for (int u = 0; u < 4; ++u) o[s][u] = p[s][u];
    mmw(p, xa, o, abase, bbase);
  }

  if (mat < nmat) {
    float* Om = OUT + (size_t)mat * 256;
#pragma unroll
    for (int s = 0; s < 4; ++s) {
      f4v vv;
#pragma unroll
      for (int u = 0; u < 4; ++u) vv[u] = 0.5f * o[s][u];
      *reinterpret_cast<f4v*>(&Om[(4 * a + s) * 16 + 4 * b]) = vv;
    }
  }
}

extern "C" void kernel_launch(void* const* d_in, const int* in_sizes, int n_in,
                              void* d_out, int out_size, void* d_ws,
                              size_t ws_size, hipStream_t stream) {
  (void)n_in; (void)out_size; (void)d_ws; (void)ws_size;
  const float* P = (const float*)d_in[0];
  float* OUT = (float*)d_out;
  const int nmat = in_sizes[0] / 256;
  const int blocks = (nmat + 15) / 16;  // 4 waves x 4 matrices per block
  spdrelu_r13<<<dim3(blocks), dim3(256), 0, stream>>>(P, OUT, nmat);
}